// Round 1
// baseline (5474.302 us; speedup 1.0000x reference)
//
#include <hip/hip_runtime.h>
#include <math.h>

// ---------------- problem constants ----------------
#define BATCH 16
#define RWS   128     // rows
#define TT    128     // time steps per row (cols*C)
#define HH    32      // hidden
#define GG    96      // 3*H gate rows
#define NBG   2       // batch groups (blocks per row)
#define BPG   8       // batches per group
#define WSTR  34      // padded LDS row stride (floats) for [96x32] mats -> 2-way (free) b64 banks

// ---------------- workspace layout (bytes) ----------------
#define H2_BYTES   (BATCH*RWS*TT*HH*4)          // 33,554,432
#define FLAG_OFF   H2_BYTES
#define PTAB_OFF   (FLAG_OFF + 1024)            // flags: RWS*NBG ints = 1024 B
#define WF_OFF     (PTAB_OFF + 258*GG*4)        // Ptab: 258*96 fp32

__device__ __forceinline__ float sigm(float x) { return 1.0f / (1.0f + __expf(-x)); }
__device__ __forceinline__ float tanhfast(float x) {
  x = fminf(fmaxf(x, -15.0f), 15.0f);
  float e = __expf(2.0f * x);
  return (e - 1.0f) / (e + 1.0f);
}

// dot over 32 elems; w from stride-34 LDS row (8B aligned), v is 32-elem LDS vector (broadcast)
__device__ __forceinline__ float dot32(const float* __restrict__ w, const float* __restrict__ v) {
  float a0 = 0.f, a1 = 0.f;
#pragma unroll
  for (int k = 0; k < HH; k += 4) {
    float2 w0 = *(const float2*)(w + k);
    float2 w1 = *(const float2*)(w + k + 2);
    float2 v0 = *(const float2*)(v + k);
    float2 v1 = *(const float2*)(v + k + 2);
    a0 = fmaf(w0.x, v0.x, fmaf(w0.y, v0.y, a0));
    a1 = fmaf(w1.x, v1.x, fmaf(w1.y, v1.y, a1));
  }
  return a0 + a1;
}

// ------------------------------------------------------------------
// prep: P[v][g] = b_ih0[g] + sum_k<64 Wih0[g][k] emb[v][k] + sum_k<65 Wih0[g][k] b_h2e[k]
//       Wf[g][j] = sum_k<65 Wih0[g][k] Wh2e[k][j]
// ------------------------------------------------------------------
__global__ __launch_bounds__(128)
void prep_kernel(const float* __restrict__ emb, const float* __restrict__ wih0,
                 const float* __restrict__ bih0, const float* __restrict__ wh2e,
                 const float* __restrict__ bh2e, float* __restrict__ Ptab,
                 float* __restrict__ Wfo) {
  const int blk = blockIdx.x, tid = threadIdx.x;
  if (blk < 258) {
    if (tid < GG) {
      const float* wr = wih0 + tid * 65;
      const float* e  = emb + blk * 64;
      float acc = bih0[tid];
      for (int k = 0; k < 64; ++k) acc = fmaf(wr[k], e[k], acc);
      for (int k = 0; k < 65; ++k) acc = fmaf(wr[k], bh2e[k], acc);
      Ptab[blk * GG + tid] = acc;
    }
  } else {
    const int g = blk - 258;
    if (tid < HH) {
      const float* wr = wih0 + g * 65;
      float acc = 0.f;
      for (int k = 0; k < 65; ++k) acc = fmaf(wr[k], wh2e[k * HH + tid], acc);
      Wfo[g * HH + tid] = acc;
    }
  }
}

// ------------------------------------------------------------------
// RNN wavefront kernel: 256 blocks = (row, batch-half); 256 thr = (j, b)
// ------------------------------------------------------------------
__device__ __forceinline__ void loadmat(const float* __restrict__ src, float* __restrict__ dst, int tid) {
  for (int i = tid; i < GG * HH; i += 256) dst[(i >> 5) * WSTR + (i & 31)] = src[i];
}

__global__ __launch_bounds__(256)
void rnn_kernel(const int* __restrict__ xg, const float* __restrict__ wih0,
                const float* __restrict__ whh0g, const float* __restrict__ bhh0g,
                const float* __restrict__ wih1g, const float* __restrict__ whh1g,
                const float* __restrict__ bih1g, const float* __restrict__ bhh1g,
                const float* __restrict__ wih2g, const float* __restrict__ whh2g,
                const float* __restrict__ bih2g, const float* __restrict__ bhh2g,
                const float* __restrict__ Ptab, const float* __restrict__ Wfg,
                float* __restrict__ h2buf, int* __restrict__ flags) {
  extern __shared__ float lds[];
  float* Wf    = lds;                 // 96*34
  float* Whh0  = Wf   + GG * WSTR;
  float* Wih1  = Whh0 + GG * WSTR;
  float* Whh1  = Wih1 + GG * WSTR;
  float* Wih2  = Whh1 + GG * WSTR;
  float* Whh2  = Wih2 + GG * WSTR;
  float* bias  = Whh2 + GG * WSTR;    // [bhh0|bih1|bhh1|bih2|bhh2] 5*96
  float* rp    = bias + 5 * GG;       // 96
  float* prevs = rp + GG;             // 8*32
  float* h0s   = prevs + BPG * HH;
  float* h1s   = h0s + BPG * HH;
  float* h2s   = h1s + BPG * HH;

  const int tid = threadIdx.x;
  const int r   = blockIdx.x & (RWS - 1);
  const int bg  = blockIdx.x >> 7;
  const int j   = tid & 31;
  const int b   = tid >> 5;
  const int bglob = bg * BPG + b;

  loadmat(Wfg,   Wf,   tid);
  loadmat(whh0g, Whh0, tid);
  loadmat(wih1g, Wih1, tid);
  loadmat(whh1g, Whh1, tid);
  loadmat(wih2g, Wih2, tid);
  loadmat(whh2g, Whh2, tid);
  {
    const float rowpos = (float)r * (2.0f / 128.0f) - 1.0f;
    for (int i = tid; i < GG; i += 256) {
      bias[i]          = bhh0g[i];
      bias[GG + i]     = bih1g[i];
      bias[2 * GG + i] = bhh1g[i];
      bias[3 * GG + i] = bih2g[i];
      bias[4 * GG + i] = bhh2g[i];
      rp[i] = wih0[i * 65 + 64] * rowpos;
    }
  }
  h0s[tid] = 0.f; h1s[tid] = 0.f; h2s[tid] = 0.f; prevs[tid] = 0.f;
  __syncthreads();

  float h0r = 0.f, h1r = 0.f, h2r = 0.f;
  const size_t xbase = (size_t)(bglob * RWS + r) * TT;
  const size_t obase = (size_t)(bglob * RWS + r) * TT * HH + j;
  const size_t pbase = (r > 0) ? ((size_t)(bglob * RWS + (r - 1)) * TT * HH + j) : 0;
  int* myflag = flags + r * NBG + bg;
  const int* pflag = (r > 0) ? (flags + (r - 1) * NBG + bg) : flags;
  const float* hb0 = h0s + b * HH;
  const float* hb1 = h1s + b * HH;
  const float* hb2 = h2s + b * HH;
  const float* pb  = prevs + b * HH;

  int vcur = xg[xbase];

  for (int t = 0; t < TT; ++t) {
    // prefetch next token + P-table rows (independent of the flag wait)
    int vnext = (t < TT - 1) ? xg[xbase + t + 1] : 0;
    float Pr = Ptab[vcur * GG + j];
    float Pz = Ptab[vcur * GG + 32 + j];
    float Pn = Ptab[vcur * GG + 64 + j];

    if (r > 0) {
      if (tid == 0) {
        const int want = t + 1;
        while (__hip_atomic_load(pflag, __ATOMIC_ACQUIRE, __HIP_MEMORY_SCOPE_AGENT) < want)
          __builtin_amdgcn_s_sleep(1);
      }
      __syncthreads();
    }
    float pv = 0.f;
    if (r > 0)
      pv = __hip_atomic_load(h2buf + pbase + (size_t)t * HH, __ATOMIC_RELAXED, __HIP_MEMORY_SCOPE_AGENT);

    // gh dots for all 3 layers use last step's h (already in LDS) -> hides pv latency
    float ghr0 = bias[j]          + dot32(Whh0 + j * WSTR, hb0);
    float ghz0 = bias[32 + j]     + dot32(Whh0 + (32 + j) * WSTR, hb0);
    float ghn0 = bias[64 + j]     + dot32(Whh0 + (64 + j) * WSTR, hb0);
    float ghr1 = bias[2*GG + j]      + dot32(Whh1 + j * WSTR, hb1);
    float ghz1 = bias[2*GG + 32 + j] + dot32(Whh1 + (32 + j) * WSTR, hb1);
    float ghn1 = bias[2*GG + 64 + j] + dot32(Whh1 + (64 + j) * WSTR, hb1);
    float ghr2 = bias[4*GG + j]      + dot32(Whh2 + j * WSTR, hb2);
    float ghz2 = bias[4*GG + 32 + j] + dot32(Whh2 + (32 + j) * WSTR, hb2);
    float ghn2 = bias[4*GG + 64 + j] + dot32(Whh2 + (64 + j) * WSTR, hb2);

    prevs[b * HH + j] = pv;
    __syncthreads();  // A: prevs ready; gh reads of h*s done

    // layer 0: gi = P[v] + rp + Wf@prev
    {
      float gir = Pr + rp[j]        + dot32(Wf + j * WSTR, pb);
      float giz = Pz + rp[32 + j]   + dot32(Wf + (32 + j) * WSTR, pb);
      float gin = Pn + rp[64 + j]   + dot32(Wf + (64 + j) * WSTR, pb);
      float rg = sigm(gir + ghr0);
      float zg = sigm(giz + ghz0);
      float ng = tanhfast(gin + rg * ghn0);
      h0r = (1.f - zg) * ng + zg * h0r;
    }
    h0s[b * HH + j] = h0r;
    __syncthreads();  // B

    // layer 1
    {
      float gir = bias[GG + j]        + dot32(Wih1 + j * WSTR, hb0);
      float giz = bias[GG + 32 + j]   + dot32(Wih1 + (32 + j) * WSTR, hb0);
      float gin = bias[GG + 64 + j]   + dot32(Wih1 + (64 + j) * WSTR, hb0);
      float rg = sigm(gir + ghr1);
      float zg = sigm(giz + ghz1);
      float ng = tanhfast(gin + rg * ghn1);
      h1r = (1.f - zg) * ng + zg * h1r;
    }
    h1s[b * HH + j] = h1r;
    __syncthreads();  // C

    // layer 2
    {
      float gir = bias[3*GG + j]        + dot32(Wih2 + j * WSTR, hb1);
      float giz = bias[3*GG + 32 + j]   + dot32(Wih2 + (32 + j) * WSTR, hb1);
      float gin = bias[3*GG + 64 + j]   + dot32(Wih2 + (64 + j) * WSTR, hb1);
      float rg = sigm(gir + ghr2);
      float zg = sigm(giz + ghz2);
      float ng = tanhfast(gin + rg * ghn2);
      h2r = (1.f - zg) * ng + zg * h2r;
    }
    h2s[b * HH + j] = h2r;
    h2buf[obase + (size_t)t * HH] = h2r;
    __threadfence();
    __syncthreads();  // D
    if (tid == 0)
      __hip_atomic_store(myflag, t + 1, __ATOMIC_RELEASE, __HIP_MEMORY_SCOPE_AGENT);

    vcur = vnext;
  }
}

// ------------------------------------------------------------------
// projection: pred[pos][v] = b_out[v] + w_out[v] . h2[pos]
// 8192 blocks x 32 positions; stage in LDS for coalesced writes
// ------------------------------------------------------------------
__global__ __launch_bounds__(256)
void proj_kernel(const float* __restrict__ h2buf, const float* __restrict__ wout,
                 const float* __restrict__ bout, float* __restrict__ out) {
  __shared__ float stage[32 * 258];
  const int tid = threadIdx.x;
  const int p = tid & 31, vq = tid >> 5;   // 8 vq groups
  const size_t pos = (size_t)blockIdx.x * 32 + p;
  const float* hrow = h2buf + pos * HH;
  float h[HH];
#pragma unroll
  for (int k = 0; k < HH; k += 4) {
    float4 f = *(const float4*)(hrow + k);
    h[k] = f.x; h[k + 1] = f.y; h[k + 2] = f.z; h[k + 3] = f.w;
  }
#pragma unroll 1
  for (int vi = 0; vi <= 32; ++vi) {
    int v = vq + vi * 8;
    if (v < 258) {
      const float* wrow = wout + v * HH;   // wave-uniform per vq group -> broadcast, L1-resident
      float a0 = bout[v], a1 = 0.f;
#pragma unroll
      for (int k = 0; k < HH; k += 4) {
        float4 w = *(const float4*)(wrow + k);
        a0 = fmaf(w.x, h[k],     fmaf(w.y, h[k + 1], a0));
        a1 = fmaf(w.z, h[k + 2], fmaf(w.w, h[k + 3], a1));
      }
      stage[p * 258 + v] = a0 + a1;
    }
  }
  __syncthreads();
  float* o = out + (size_t)blockIdx.x * 32 * 258;
#pragma unroll 1
  for (int i = tid; i < 32 * 258; i += 256) o[i] = stage[i];
}

// ------------------------------------------------------------------
extern "C" void kernel_launch(void* const* d_in, const int* in_sizes, int n_in,
                              void* d_out, int out_size, void* d_ws, size_t ws_size,
                              hipStream_t stream) {
  const int*   x    = (const int*)d_in[0];
  const float* emb  = (const float*)d_in[1];
  const float* wih0 = (const float*)d_in[2];
  const float* whh0 = (const float*)d_in[3];
  const float* bih0 = (const float*)d_in[4];
  const float* bhh0 = (const float*)d_in[5];
  const float* wih1 = (const float*)d_in[6];
  const float* whh1 = (const float*)d_in[7];
  const float* bih1 = (const float*)d_in[8];
  const float* bhh1 = (const float*)d_in[9];
  const float* wih2 = (const float*)d_in[10];
  const float* whh2 = (const float*)d_in[11];
  const float* bih2 = (const float*)d_in[12];
  const float* bhh2 = (const float*)d_in[13];
  const float* wh2e = (const float*)d_in[14];
  const float* bh2e = (const float*)d_in[15];
  const float* wout = (const float*)d_in[16];
  const float* bout = (const float*)d_in[17];
  float* out = (float*)d_out;

  char*  ws    = (char*)d_ws;
  float* h2buf = (float*)ws;
  int*   flags = (int*)(ws + FLAG_OFF);
  float* Ptab  = (float*)(ws + PTAB_OFF);
  float* Wf    = (float*)(ws + WF_OFF);

  hipMemsetAsync(flags, 0, RWS * NBG * sizeof(int), stream);
  prep_kernel<<<354, 128, 0, stream>>>(emb, wih0, bih0, wh2e, bh2e, Ptab, Wf);

  const int rnn_lds_bytes = (6 * GG * WSTR + 5 * GG + GG + 4 * BPG * HH) * 4;  // 84,736 B
  hipFuncSetAttribute((const void*)rnn_kernel,
                      hipFuncAttributeMaxDynamicSharedMemorySize, rnn_lds_bytes);
  rnn_kernel<<<256, 256, rnn_lds_bytes, stream>>>(
      x, wih0, whh0, bhh0, wih1, whh1, bih1, bhh1, wih2, whh2, bih2, bhh2,
      Ptab, Wf, h2buf, flags);

  proj_kernel<<<8192, 256, 0, stream>>>(h2buf, wout, bout, out);
}

// Round 2
// 1811.000 us; speedup vs baseline: 3.0228x; 3.0228x over previous
//
#include <hip/hip_runtime.h>
#include <math.h>

// ---------------- problem constants ----------------
#define BATCH 16
#define RWS   128     // rows
#define TT    128     // time steps per row (cols*C)
#define HH    32      // hidden
#define GG    96      // 3*H gate rows
#define NBG   2       // batch groups (blocks per row)
#define BPG   8       // batches per group
#define WSTR  34      // padded LDS row stride (floats) for [96x32] mats -> 2-way (free) b64 banks
#define FSTR  16      // flag stride in ints (64 B) to avoid coherence-line ping-pong

// ---------------- workspace layout (bytes) ----------------
#define H2_BYTES   (BATCH*RWS*TT*HH*4)          // 33,554,432
#define FLAG_OFF   H2_BYTES
#define FLAG_BYTES (RWS*NBG*FSTR*4)             // 16,384
#define PTAB_OFF   (FLAG_OFF + FLAG_BYTES)
#define WF_OFF     (PTAB_OFF + 258*GG*4)        // Ptab: 258*96 fp32

__device__ __forceinline__ float sigm(float x) { return 1.0f / (1.0f + __expf(-x)); }
__device__ __forceinline__ float tanhfast(float x) {
  x = fminf(fmaxf(x, -15.0f), 15.0f);
  float e = __expf(2.0f * x);
  return (e - 1.0f) / (e + 1.0f);
}

// dot over 32 elems; w from stride-34 LDS row (8B aligned), v is 32-elem LDS vector (broadcast)
__device__ __forceinline__ float dot32(const float* __restrict__ w, const float* __restrict__ v) {
  float a0 = 0.f, a1 = 0.f;
#pragma unroll
  for (int k = 0; k < HH; k += 4) {
    float2 w0 = *(const float2*)(w + k);
    float2 w1 = *(const float2*)(w + k + 2);
    float2 v0 = *(const float2*)(v + k);
    float2 v1 = *(const float2*)(v + k + 2);
    a0 = fmaf(w0.x, v0.x, fmaf(w0.y, v0.y, a0));
    a1 = fmaf(w1.x, v1.x, fmaf(w1.y, v1.y, a1));
  }
  return a0 + a1;
}

// ------------------------------------------------------------------
// prep: P[v][g] = b_ih0[g] + sum_k<64 Wih0[g][k] emb[v][k] + sum_k<65 Wih0[g][k] b_h2e[k]
//       Wf[g][j] = sum_k<65 Wih0[g][k] Wh2e[k][j]
// ------------------------------------------------------------------
__global__ __launch_bounds__(128)
void prep_kernel(const float* __restrict__ emb, const float* __restrict__ wih0,
                 const float* __restrict__ bih0, const float* __restrict__ wh2e,
                 const float* __restrict__ bh2e, float* __restrict__ Ptab,
                 float* __restrict__ Wfo) {
  const int blk = blockIdx.x, tid = threadIdx.x;
  if (blk < 258) {
    if (tid < GG) {
      const float* wr = wih0 + tid * 65;
      const float* e  = emb + blk * 64;
      float acc = bih0[tid];
      for (int k = 0; k < 64; ++k) acc = fmaf(wr[k], e[k], acc);
      for (int k = 0; k < 65; ++k) acc = fmaf(wr[k], bh2e[k], acc);
      Ptab[blk * GG + tid] = acc;
    }
  } else {
    const int g = blk - 258;
    if (tid < HH) {
      const float* wr = wih0 + g * 65;
      float acc = 0.f;
      for (int k = 0; k < 65; ++k) acc = fmaf(wr[k], wh2e[k * HH + tid], acc);
      Wfo[g * HH + tid] = acc;
    }
  }
}

// ------------------------------------------------------------------
// RNN wavefront kernel: 256 blocks = (row, batch-half); 256 thr = (j, b)
// Cross-row comms: ALL via relaxed agent-scope atomics (sc-flagged vmem that
// hits the coherence point directly) -- NO threadfence / acquire / release,
// which on gfx950 lower to buffer_wbl2/buffer_inv L2-scan ops (~10us each,
// the R0 bottleneck). Data->flag ordering comes from __syncthreads()'s
// implicit s_waitcnt vmcnt(0) drain before s_barrier.
// ------------------------------------------------------------------
__device__ __forceinline__ void loadmat(const float* __restrict__ src, float* __restrict__ dst, int tid) {
  for (int i = tid; i < GG * HH; i += 256) dst[(i >> 5) * WSTR + (i & 31)] = src[i];
}

__global__ __launch_bounds__(256)
void rnn_kernel(const int* __restrict__ xg, const float* __restrict__ wih0,
                const float* __restrict__ whh0g, const float* __restrict__ bhh0g,
                const float* __restrict__ wih1g, const float* __restrict__ whh1g,
                const float* __restrict__ bih1g, const float* __restrict__ bhh1g,
                const float* __restrict__ wih2g, const float* __restrict__ whh2g,
                const float* __restrict__ bih2g, const float* __restrict__ bhh2g,
                const float* __restrict__ Ptab, const float* __restrict__ Wfg,
                float* __restrict__ h2buf, int* __restrict__ flags) {
  extern __shared__ float lds[];
  float* Wf    = lds;                 // 96*34
  float* Whh0  = Wf   + GG * WSTR;
  float* Wih1  = Whh0 + GG * WSTR;
  float* Whh1  = Wih1 + GG * WSTR;
  float* Wih2  = Whh1 + GG * WSTR;
  float* Whh2  = Wih2 + GG * WSTR;
  float* bias  = Whh2 + GG * WSTR;    // [bhh0|bih1|bhh1|bih2|bhh2] 5*96
  float* rp    = bias + 5 * GG;       // 96
  float* prevs = rp + GG;             // 8*32
  float* h0s   = prevs + BPG * HH;
  float* h1s   = h0s + BPG * HH;
  float* h2s   = h1s + BPG * HH;

  const int tid = threadIdx.x;
  const int r   = blockIdx.x & (RWS - 1);
  const int bg  = blockIdx.x >> 7;
  const int j   = tid & 31;
  const int b   = tid >> 5;
  const int bglob = bg * BPG + b;

  loadmat(Wfg,   Wf,   tid);
  loadmat(whh0g, Whh0, tid);
  loadmat(wih1g, Wih1, tid);
  loadmat(whh1g, Whh1, tid);
  loadmat(wih2g, Wih2, tid);
  loadmat(whh2g, Whh2, tid);
  {
    const float rowpos = (float)r * (2.0f / 128.0f) - 1.0f;
    for (int i = tid; i < GG; i += 256) {
      bias[i]          = bhh0g[i];
      bias[GG + i]     = bih1g[i];
      bias[2 * GG + i] = bhh1g[i];
      bias[3 * GG + i] = bih2g[i];
      bias[4 * GG + i] = bhh2g[i];
      rp[i] = wih0[i * 65 + 64] * rowpos;
    }
  }
  h0s[tid] = 0.f; h1s[tid] = 0.f; h2s[tid] = 0.f; prevs[tid] = 0.f;
  __syncthreads();

  float h0r = 0.f, h1r = 0.f, h2r = 0.f;
  const size_t xbase = (size_t)(bglob * RWS + r) * TT;
  const size_t obase = (size_t)(bglob * RWS + r) * TT * HH + j;
  const size_t pbase = (r > 0) ? ((size_t)(bglob * RWS + (r - 1)) * TT * HH + j) : 0;
  int* myflag = flags + (r * NBG + bg) * FSTR;
  const int* pflag = (r > 0) ? (flags + ((r - 1) * NBG + bg) * FSTR) : flags;
  const float* hb0 = h0s + b * HH;
  const float* hb1 = h1s + b * HH;
  const float* hb2 = h2s + b * HH;
  const float* pb  = prevs + b * HH;

  int vcur = xg[xbase];

  for (int t = 0; t < TT; ++t) {
    // prefetch next token + P-table rows (independent of the flag wait)
    int vnext = (t < TT - 1) ? xg[xbase + t + 1] : 0;
    float Pr = Ptab[vcur * GG + j];
    float Pz = Ptab[vcur * GG + 32 + j];
    float Pn = Ptab[vcur * GG + 64 + j];

    if (r > 0) {
      if (tid == 0) {
        const int want = t + 1;
        while (__hip_atomic_load(pflag, __ATOMIC_RELAXED, __HIP_MEMORY_SCOPE_AGENT) < want)
          __builtin_amdgcn_s_sleep(1);
      }
      __syncthreads();
    }
    float pv = 0.f;
    if (r > 0)
      pv = __hip_atomic_load(h2buf + pbase + (size_t)t * HH, __ATOMIC_RELAXED, __HIP_MEMORY_SCOPE_AGENT);

    // gh dots for all 3 layers use last step's h (already in LDS) -> hides pv latency
    float ghr0 = bias[j]          + dot32(Whh0 + j * WSTR, hb0);
    float ghz0 = bias[32 + j]     + dot32(Whh0 + (32 + j) * WSTR, hb0);
    float ghn0 = bias[64 + j]     + dot32(Whh0 + (64 + j) * WSTR, hb0);
    float ghr1 = bias[2*GG + j]      + dot32(Whh1 + j * WSTR, hb1);
    float ghz1 = bias[2*GG + 32 + j] + dot32(Whh1 + (32 + j) * WSTR, hb1);
    float ghn1 = bias[2*GG + 64 + j] + dot32(Whh1 + (64 + j) * WSTR, hb1);
    float ghr2 = bias[4*GG + j]      + dot32(Whh2 + j * WSTR, hb2);
    float ghz2 = bias[4*GG + 32 + j] + dot32(Whh2 + (32 + j) * WSTR, hb2);
    float ghn2 = bias[4*GG + 64 + j] + dot32(Whh2 + (64 + j) * WSTR, hb2);

    prevs[b * HH + j] = pv;
    __syncthreads();  // A: prevs ready; gh reads of h*s done

    // layer 0: gi = P[v] + rp + Wf@prev
    {
      float gir = Pr + rp[j]        + dot32(Wf + j * WSTR, pb);
      float giz = Pz + rp[32 + j]   + dot32(Wf + (32 + j) * WSTR, pb);
      float gin = Pn + rp[64 + j]   + dot32(Wf + (64 + j) * WSTR, pb);
      float rg = sigm(gir + ghr0);
      float zg = sigm(giz + ghz0);
      float ng = tanhfast(gin + rg * ghn0);
      h0r = (1.f - zg) * ng + zg * h0r;
    }
    h0s[b * HH + j] = h0r;
    __syncthreads();  // B

    // layer 1
    {
      float gir = bias[GG + j]        + dot32(Wih1 + j * WSTR, hb0);
      float giz = bias[GG + 32 + j]   + dot32(Wih1 + (32 + j) * WSTR, hb0);
      float gin = bias[GG + 64 + j]   + dot32(Wih1 + (64 + j) * WSTR, hb0);
      float rg = sigm(gir + ghr1);
      float zg = sigm(giz + ghz1);
      float ng = tanhfast(gin + rg * ghn1);
      h1r = (1.f - zg) * ng + zg * h1r;
    }
    h1s[b * HH + j] = h1r;
    __syncthreads();  // C

    // layer 2
    {
      float gir = bias[3*GG + j]        + dot32(Wih2 + j * WSTR, hb1);
      float giz = bias[3*GG + 32 + j]   + dot32(Wih2 + (32 + j) * WSTR, hb1);
      float gin = bias[3*GG + 64 + j]   + dot32(Wih2 + (64 + j) * WSTR, hb1);
      float rg = sigm(gir + ghr2);
      float zg = sigm(giz + ghz2);
      float ng = tanhfast(gin + rg * ghn2);
      h2r = (1.f - zg) * ng + zg * h2r;
    }
    h2s[b * HH + j] = h2r;
    // write-through to coherence point (relaxed agent atomic => sc-flagged
    // store, no cache-maintenance op). Barrier D's implicit vmcnt(0) drain
    // guarantees all 4 waves' stores completed before tid0 publishes flag.
    __hip_atomic_store(h2buf + obase + (size_t)t * HH, h2r,
                       __ATOMIC_RELAXED, __HIP_MEMORY_SCOPE_AGENT);
    __syncthreads();  // D
    if (tid == 0)
      __hip_atomic_store(myflag, t + 1, __ATOMIC_RELAXED, __HIP_MEMORY_SCOPE_AGENT);

    vcur = vnext;
  }
}

// ------------------------------------------------------------------
// projection: pred[pos][v] = b_out[v] + w_out[v] . h2[pos]
// 8192 blocks x 32 positions; stage in LDS for coalesced writes
// ------------------------------------------------------------------
__global__ __launch_bounds__(256)
void proj_kernel(const float* __restrict__ h2buf, const float* __restrict__ wout,
                 const float* __restrict__ bout, float* __restrict__ out) {
  __shared__ float stage[32 * 258];
  const int tid = threadIdx.x;
  const int p = tid & 31, vq = tid >> 5;   // 8 vq groups
  const size_t pos = (size_t)blockIdx.x * 32 + p;
  const float* hrow = h2buf + pos * HH;
  float h[HH];
#pragma unroll
  for (int k = 0; k < HH; k += 4) {
    float4 f = *(const float4*)(hrow + k);
    h[k] = f.x; h[k + 1] = f.y; h[k + 2] = f.z; h[k + 3] = f.w;
  }
#pragma unroll 1
  for (int vi = 0; vi <= 32; ++vi) {
    int v = vq + vi * 8;
    if (v < 258) {
      const float* wrow = wout + v * HH;   // wave-uniform per vq group -> broadcast, L1-resident
      float a0 = bout[v], a1 = 0.f;
#pragma unroll
      for (int k = 0; k < HH; k += 4) {
        float4 w = *(const float4*)(wrow + k);
        a0 = fmaf(w.x, h[k],     fmaf(w.y, h[k + 1], a0));
        a1 = fmaf(w.z, h[k + 2], fmaf(w.w, h[k + 3], a1));
      }
      stage[p * 258 + v] = a0 + a1;
    }
  }
  __syncthreads();
  float* o = out + (size_t)blockIdx.x * 32 * 258;
#pragma unroll 1
  for (int i = tid; i < 32 * 258; i += 256) o[i] = stage[i];
}

// ------------------------------------------------------------------
extern "C" void kernel_launch(void* const* d_in, const int* in_sizes, int n_in,
                              void* d_out, int out_size, void* d_ws, size_t ws_size,
                              hipStream_t stream) {
  const int*   x    = (const int*)d_in[0];
  const float* emb  = (const float*)d_in[1];
  const float* wih0 = (const float*)d_in[2];
  const float* whh0 = (const float*)d_in[3];
  const float* bih0 = (const float*)d_in[4];
  const float* bhh0 = (const float*)d_in[5];
  const float* wih1 = (const float*)d_in[6];
  const float* whh1 = (const float*)d_in[7];
  const float* bih1 = (const float*)d_in[8];
  const float* bhh1 = (const float*)d_in[9];
  const float* wih2 = (const float*)d_in[10];
  const float* whh2 = (const float*)d_in[11];
  const float* bih2 = (const float*)d_in[12];
  const float* bhh2 = (const float*)d_in[13];
  const float* wh2e = (const float*)d_in[14];
  const float* bh2e = (const float*)d_in[15];
  const float* wout = (const float*)d_in[16];
  const float* bout = (const float*)d_in[17];
  float* out = (float*)d_out;

  char*  ws    = (char*)d_ws;
  float* h2buf = (float*)ws;
  int*   flags = (int*)(ws + FLAG_OFF);
  float* Ptab  = (float*)(ws + PTAB_OFF);
  float* Wf    = (float*)(ws + WF_OFF);

  hipMemsetAsync(flags, 0, FLAG_BYTES, stream);
  prep_kernel<<<354, 128, 0, stream>>>(emb, wih0, bih0, wh2e, bh2e, Ptab, Wf);

  const int rnn_lds_bytes = (6 * GG * WSTR + 5 * GG + GG + 4 * BPG * HH) * 4;  // 84,736 B
  hipFuncSetAttribute((const void*)rnn_kernel,
                      hipFuncAttributeMaxDynamicSharedMemorySize, rnn_lds_bytes);
  rnn_kernel<<<256, 256, rnn_lds_bytes, stream>>>(
      x, wih0, whh0, bhh0, wih1, whh1, bih1, bhh1, wih2, whh2, bih2, bhh2,
      Ptab, Wf, h2buf, flags);

  proj_kernel<<<8192, 256, 0, stream>>>(h2buf, wout, bout, out);
}